// Round 10
// baseline (179.084 us; speedup 1.0000x reference)
//
#include <hip/hip_runtime.h>
#include <hip/hip_cooperative_groups.h>
#include <math.h>

namespace cg = cooperative_groups;

#define N_PTS 12000
#define NT_CHUNKS 150
#define CHUNK 80             // N_TAR / NT_CHUNKS (exact)
#define GROUPS 6             // source groups: 6*2048 = 12288 >= 12000
#define SRC_PER_GROUP 2048   // 256 threads * 8 src each (clamped tail)
#define GRID_BLOCKS (NT_CHUNKS * GROUPS)   // 900
#define MAH_BLOCKS 188       // ceil(12000/64) : 64 sources per block
#define RES_PER_WAVE 20      // CHUNK / 4 waves

// ---------------------------------------------------------------------------
// Single cooperative kernel, one graph node.
// Phase 1 (all 900 blocks): R5's proven NN partial-min tile. Block b ->
//   (chunk = b/6, group = b%6). Targets staged in LDS as [x,y,z,|t3|^2];
//   score(i,j) = |tar_j3|^2 - 2*dot3(tsrc_i, tar_j) (argmin-equivalent to
//   reference d2; tar.w == 1 exactly). VALUE only; explicit fmaf chains so
//   phase 2's rescan recomputes bit-identical scores.
// grid.sync()  (cooperative launch -> all blocks co-resident: 900 <= 1024)
// Phase 2 (blocks 0..187): R5's proven 4-wave mah: chunk combine with
//   (val, chunk) lexicographic min -> rescan winning chunk 20/wave with
//   (val, j) lexicographic min = reference first-argmin -> covariance
//   congruence + 3x3 adjugate inverse + Mahalanobis -> block reduce ->
//   counter-gated last-block fixed-order final reduce (deterministic).
// ---------------------------------------------------------------------------
__global__ __launch_bounds__(256, 4) void gicp_coop_kernel(
    const float* __restrict__ T,
    const float* __restrict__ src,
    const float* __restrict__ tar,
    const float* __restrict__ cs,   // covs_src [N][16]
    const float* __restrict__ ct,   // covs_tar [N][16]
    float* __restrict__ pval,
    float* __restrict__ bsum,
    unsigned int* __restrict__ counter,
    float* __restrict__ out)
{
    __shared__ float4 stage[CHUNK];
    __shared__ float  lds_v[4][64];
    __shared__ int    lds_i[4][64];

    const int bid = blockIdx.x;
    const int tid = threadIdx.x;
    const float4* tar4 = (const float4*)tar;

    // ================= Phase 1: NN partial min =================
    {
        const int chunk = bid / GROUPS;
        const int group = bid % GROUPS;
        const int jbase = chunk * CHUNK;

        if (bid == 0 && tid == 0) atomicExch(counter, 0u);

        const float T00=T[0],  T01=T[1],  T02=T[2],  T03=T[3];
        const float T10=T[4],  T11=T[5],  T12=T[6],  T13=T[7];
        const float T20=T[8],  T21=T[9],  T22=T[10], T23=T[11];

        if (tid < CHUNK) {
            float4 t = tar4[jbase + tid];
            float n3 = fmaf(t.x, t.x, fmaf(t.y, t.y, t.z * t.z));
            stage[tid] = make_float4(t.x, t.y, t.z, n3);
        }
        __syncthreads();

        float sx[8], sy[8], sz[8], mval[8];
        const int base = group * SRC_PER_GROUP + tid;
        #pragma unroll
        for (int k = 0; k < 8; ++k) {
            int i = base + k * 256;
            if (i >= N_PTS) i = N_PTS - 1;      // clamp (write is guarded)
            float4 p = ((const float4*)src)[i];
            float tx = fmaf(T00, p.x, fmaf(T01, p.y, fmaf(T02, p.z, T03 * p.w)));
            float ty = fmaf(T10, p.x, fmaf(T11, p.y, fmaf(T12, p.z, T13 * p.w)));
            float tz = fmaf(T20, p.x, fmaf(T21, p.y, fmaf(T22, p.z, T23 * p.w)));
            sx[k] = -2.0f * tx;
            sy[k] = -2.0f * ty;
            sz[k] = -2.0f * tz;
            mval[k] = INFINITY;
        }

        #pragma unroll 4
        for (int j = 0; j < CHUNK; ++j) {
            const float4 t = stage[j];
            #pragma unroll
            for (int k = 0; k < 8; ++k) {
                float s = fmaf(sx[k], t.x, fmaf(sy[k], t.y, fmaf(sz[k], t.z, t.w)));
                mval[k] = fminf(mval[k], s);
            }
        }

        #pragma unroll
        for (int k = 0; k < 8; ++k) {
            int i = base + k * 256;
            if (i < N_PTS) pval[chunk * N_PTS + i] = mval[k];
        }
        __threadfence();                        // make pval device-visible
    }

    cg::this_grid().sync();

    // ================= Phase 2: mah + finalize (blocks 0..187) =========
    if (bid < MAH_BLOCKS) {
        const int lane = tid & 63;
        const int wv   = tid >> 6;
        const int i    = bid * 64 + lane;
        const int ic   = (i < N_PTS) ? i : (N_PTS - 1);

        // --- Phase A: per-wave chunk-subset reduce (coalesced) ---
        float bv = INFINITY; int bc = 0;
        #pragma unroll 8
        for (int c = wv; c < NT_CHUNKS; c += 4) {
            float v = pval[c * N_PTS + ic];
            if (v < bv) { bv = v; bc = c; }
        }
        lds_v[wv][lane] = bv;
        lds_i[wv][lane] = bc;
        __syncthreads();

        // --- Phase B: lexicographic (val, chunk) min across waves ---
        float cv = lds_v[0][lane]; int cc = lds_i[0][lane];
        #pragma unroll
        for (int w = 1; w < 4; ++w) {
            float v = lds_v[w][lane]; int c = lds_i[w][lane];
            if (v < cv || (v == cv && c < cc)) { cv = v; cc = c; }
        }
        __syncthreads();

        // --- Phase C: rescan winning chunk, 20 targets per wave ---
        float Tm[4][4];
        #pragma unroll
        for (int a = 0; a < 16; ++a) ((float*)Tm)[a] = T[a];

        const float4 p = ((const float4*)src)[ic];
        const float tx = fmaf(Tm[0][0], p.x, fmaf(Tm[0][1], p.y, fmaf(Tm[0][2], p.z, Tm[0][3] * p.w)));
        const float ty = fmaf(Tm[1][0], p.x, fmaf(Tm[1][1], p.y, fmaf(Tm[1][2], p.z, Tm[1][3] * p.w)));
        const float tz = fmaf(Tm[2][0], p.x, fmaf(Tm[2][1], p.y, fmaf(Tm[2][2], p.z, Tm[2][3] * p.w)));
        const float sx = -2.0f * tx, sy = -2.0f * ty, sz = -2.0f * tz;

        const int jb = cc * CHUNK + wv * RES_PER_WAVE;
        float rv = INFINITY; int rj = 0;
        #pragma unroll 5
        for (int jj = 0; jj < RES_PER_WAVE; ++jj) {
            float4 t = tar4[jb + jj];
            float n3 = fmaf(t.x, t.x, fmaf(t.y, t.y, t.z * t.z));
            float s  = fmaf(sx, t.x, fmaf(sy, t.y, fmaf(sz, t.z, n3)));
            if (s < rv) { rv = s; rj = jb + jj; }
        }
        lds_v[wv][lane] = rv;
        lds_i[wv][lane] = rj;
        __syncthreads();

        // --- Phase D: wave 0 finishes per-source work ---
        if (wv == 0) {
            float fv = lds_v[0][lane]; int bidx = lds_i[0][lane];
            #pragma unroll
            for (int w = 1; w < 4; ++w) {
                float v = lds_v[w][lane]; int j = lds_i[w][lane];
                if (v < fv || (v == fv && j < bidx)) { fv = v; bidx = j; }
            }

            float C[4][4];
            #pragma unroll
            for (int a = 0; a < 16; ++a) ((float*)C)[a] = cs[ic * 16 + a];

            float B[4][3];
            #pragma unroll
            for (int j = 0; j < 4; ++j)
                #pragma unroll
                for (int c = 0; c < 3; ++c)
                    B[j][c] = C[j][0]*Tm[c][0] + C[j][1]*Tm[c][1]
                            + C[j][2]*Tm[c][2] + C[j][3]*Tm[c][3];

            const float* ctb = ct + (size_t)bidx * 16;
            float M[3][3];
            #pragma unroll
            for (int r = 0; r < 3; ++r)
                #pragma unroll
                for (int c = 0; c < 3; ++c)
                    M[r][c] = Tm[r][0]*B[0][c] + Tm[r][1]*B[1][c]
                            + Tm[r][2]*B[2][c] + Tm[r][3]*B[3][c]
                            + ctb[r * 4 + c];

            const float a_ = M[0][0], b_ = M[0][1], c_ = M[0][2];
            const float d_ = M[1][0], e_ = M[1][1], f_ = M[1][2];
            const float g_ = M[2][0], h_ = M[2][1], i_ = M[2][2];

            const float A0 = e_*i_ - f_*h_;
            const float A1 = f_*g_ - d_*i_;
            const float A2 = d_*h_ - e_*g_;
            const float det = a_*A0 + b_*A1 + c_*A2;
            const float rdet = 1.0f / det;

            float inv[3][3];
            inv[0][0] = A0 * rdet;
            inv[0][1] = (c_*h_ - b_*i_) * rdet;
            inv[0][2] = (b_*f_ - c_*e_) * rdet;
            inv[1][0] = A1 * rdet;
            inv[1][1] = (a_*i_ - c_*g_) * rdet;
            inv[1][2] = (c_*d_ - a_*f_) * rdet;
            inv[2][0] = A2 * rdet;
            inv[2][1] = (b_*g_ - a_*h_) * rdet;
            inv[2][2] = (a_*e_ - b_*d_) * rdet;

            // loss branch: pT = src @ T (columns of T)
            const float p0 = p.x*Tm[0][0] + p.y*Tm[1][0] + p.z*Tm[2][0] + p.w*Tm[3][0];
            const float p1 = p.x*Tm[0][1] + p.y*Tm[1][1] + p.z*Tm[2][1] + p.w*Tm[3][1];
            const float p2 = p.x*Tm[0][2] + p.y*Tm[1][2] + p.z*Tm[2][2] + p.w*Tm[3][2];

            const float4 tp = tar4[bidx];
            const float r0 = tp.x - p0;
            const float r1 = tp.y - p1;
            const float r2 = tp.z - p2;

            float mah = r0*(inv[0][0]*r0 + inv[0][1]*r1 + inv[0][2]*r2)
                      + r1*(inv[1][0]*r0 + inv[1][1]*r1 + inv[1][2]*r2)
                      + r2*(inv[2][0]*r0 + inv[2][1]*r1 + inv[2][2]*r2);
            if (i >= N_PTS) mah = 0.0f;

            // wave reduce (deterministic)
            #pragma unroll
            for (int off = 32; off > 0; off >>= 1)
                mah += __shfl_down(mah, off, 64);

            unsigned int old = 0u;
            if (lane == 0) {
                bsum[bid] = mah;
                __threadfence();
                old = atomicAdd(counter, 1u);
            }
            old = __shfl(old, 0, 64);

            // --- Phase E: last block: fixed-order final reduce ---
            if (old == MAH_BLOCKS - 1) {
                __threadfence();   // acquire
                double acc = 0.0;
                for (int s = lane; s < MAH_BLOCKS; s += 64)
                    acc += (double)atomicAdd(&bsum[s], 0.0f);   // coherent read
                #pragma unroll
                for (int off = 32; off > 0; off >>= 1)
                    acc += __shfl_down(acc, off, 64);
                if (lane == 0)
                    out[0] = (float)(acc / (double)N_PTS);
            }
        }
    }
}

extern "C" void kernel_launch(void* const* d_in, const int* in_sizes, int n_in,
                              void* d_out, int out_size, void* d_ws, size_t ws_size,
                              hipStream_t stream) {
    const float* T   = (const float*)d_in[0];
    const float* src = (const float*)d_in[1];
    const float* tar = (const float*)d_in[2];
    const float* cs  = (const float*)d_in[3];
    const float* ct  = (const float*)d_in[4];
    float* out = (float*)d_out;

    char* ws = (char*)d_ws;
    unsigned int* counter = (unsigned int*)ws;             // 4 B
    float* bsum = (float*)(ws + 256);                      // 188 floats
    float* pval = (float*)(ws + 4096);                     // 150*12000*4 = 7.2 MB

    void* args[] = {
        (void*)&T, (void*)&src, (void*)&tar, (void*)&cs, (void*)&ct,
        (void*)&pval, (void*)&bsum, (void*)&counter, (void*)&out
    };

    hipLaunchCooperativeKernel((const void*)gicp_coop_kernel,
                               dim3(GRID_BLOCKS), dim3(256),
                               args, 0, stream);
}

// Round 11
// 35.296 us; speedup vs baseline: 5.0738x; 5.0738x over previous
//
#include <hip/hip_runtime.h>
#include <math.h>

#define N_PTS 12000
#define NT_CHUNKS 150
#define CHUNK 80             // N_TAR / NT_CHUNKS (exact, even)
#define HCHUNK 40            // target pairs per chunk
#define SRC_PER_BLOCK 2048   // 256 threads * 8 src each
#define SRC_BLOCKS 6         // 6*2048 = 12288 >= 12000 (clamped tail)
#define MAH_BLOCKS 188       // ceil(12000/64)
#define RES_PER_WAVE 20      // CHUNK / 4 waves

typedef float v2f __attribute__((ext_vector_type(2)));

// ---------------------------------------------------------------------------
// Kernel 1: brute-force NN partial min (VALUE ONLY), forced packed fp32.
// Targets paired in LDS as {x0,x1,y0,y1},{z0,z1,n0,n1}; inner loop per
// source k per 2 targets: 3x v_pk_fma_f32 (inline asm, guaranteed) +
// 1x v_min3_f32 folding both halves into the running min = 2.0 VALU/pair
// (vs ~4.4 scalar).  Each pk half is an IEEE fp32 FMA with the identical
// association order as kernel 2's scalar fmaf rescan (sz*z+n3, +sy*y,
// +sx*x) -> bit-identical scores; min3 only reorders a commutative
// value-min.  score(i,j) = |tar_j3|^2 - 2*dot3(tsrc_i, tar_j):
// argmin-equivalent to reference d2 (tar.w == 1 exactly).
// Block (0,0) resets kernel 2's completion counter.
// ---------------------------------------------------------------------------
__global__ __launch_bounds__(256) void nn_partial_kernel(
    const float* __restrict__ T,
    const float* __restrict__ src,
    const float* __restrict__ tar,
    float* __restrict__ pval,
    unsigned int* __restrict__ counter)
{
    __shared__ float4 L[HCHUNK * 2];    // pair g: L[2g]={x0,x1,y0,y1}, L[2g+1]={z0,z1,n0,n1}
    const int tid   = threadIdx.x;
    const int sblk  = blockIdx.x;
    const int chunk = blockIdx.y;
    const int jbase = chunk * CHUNK;
    const float4* tar4 = (const float4*)tar;

    if (sblk == 0 && chunk == 0 && tid == 0) atomicExch(counter, 0u);

    const float T00=T[0],  T01=T[1],  T02=T[2],  T03=T[3];
    const float T10=T[4],  T11=T[5],  T12=T[6],  T13=T[7];
    const float T20=T[8],  T21=T[9],  T22=T[10], T23=T[11];

    if (tid < CHUNK) {
        float4 t = tar4[jbase + tid];
        float n3 = fmaf(t.x, t.x, fmaf(t.y, t.y, t.z * t.z));
        const int g = tid >> 1, h = tid & 1;
        float* Lg = (float*)&L[2 * g];
        Lg[0 + h] = t.x;
        Lg[2 + h] = t.y;
        Lg[4 + h] = t.z;
        Lg[6 + h] = n3;
    }
    __syncthreads();

    v2f sxp[8], syp[8], szp[8];
    float mval[8];
    const int base = sblk * SRC_PER_BLOCK + tid;
    #pragma unroll
    for (int k = 0; k < 8; ++k) {
        int i = base + k * 256;
        if (i >= N_PTS) i = N_PTS - 1;          // clamp (write is guarded)
        float4 p = ((const float4*)src)[i];
        float tx = fmaf(T00, p.x, fmaf(T01, p.y, fmaf(T02, p.z, T03 * p.w)));
        float ty = fmaf(T10, p.x, fmaf(T11, p.y, fmaf(T12, p.z, T13 * p.w)));
        float tz = fmaf(T20, p.x, fmaf(T21, p.y, fmaf(T22, p.z, T23 * p.w)));
        float sx = -2.0f * tx, sy = -2.0f * ty, sz = -2.0f * tz;
        sxp[k] = (v2f){sx, sx};
        syp[k] = (v2f){sy, sy};
        szp[k] = (v2f){sz, sz};
        mval[k] = INFINITY;
    }

    #pragma unroll 4
    for (int g = 0; g < HCHUNK; ++g) {
        const float4 A = L[2 * g];      // {x0, x1, y0, y1}
        const float4 B = L[2 * g + 1];  // {z0, z1, n0, n1}
        const v2f X = {A.x, A.y};
        const v2f Y = {A.z, A.w};
        const v2f Z = {B.x, B.y};
        const v2f N = {B.z, B.w};
        #pragma unroll
        for (int k = 0; k < 8; ++k) {
            v2f s;
            // s = Z*szp + N ; s = Y*syp + s ; s = X*sxp + s   (per-half IEEE fma,
            // same association as the scalar rescan chain)
            asm("v_pk_fma_f32 %0, %1, %2, %3" : "=v"(s) : "v"(Z), "v"(szp[k]), "v"(N));
            asm("v_pk_fma_f32 %0, %1, %2, %3" : "=v"(s) : "v"(Y), "v"(syp[k]), "v"(s));
            asm("v_pk_fma_f32 %0, %1, %2, %3" : "=v"(s) : "v"(X), "v"(sxp[k]), "v"(s));
            // mval = min(mval, s.lo, s.hi)
            asm("v_min3_f32 %0, %1, %2, %3"
                : "=v"(mval[k]) : "v"(mval[k]), "v"(s.x), "v"(s.y));
        }
    }

    #pragma unroll
    for (int k = 0; k < 8; ++k) {
        int i = base + k * 256;
        if (i < N_PTS) pval[chunk * N_PTS + i] = mval[k];
    }
}

// ---------------------------------------------------------------------------
// Kernel 2: identical to the proven R5 version. 64 sources per block
// (lane = source), 4 waves split the work.
// ---------------------------------------------------------------------------
__global__ __launch_bounds__(256) void mah_finalize_kernel(
    const float* __restrict__ T,
    const float* __restrict__ src,
    const float* __restrict__ tar,
    const float* __restrict__ cs,   // covs_src  [N][16]
    const float* __restrict__ ct,   // covs_tar  [N][16]
    const float* __restrict__ pval,
    float* __restrict__ bsum,
    unsigned int* __restrict__ counter,
    float* __restrict__ out)
{
    __shared__ float lds_v[4][64];
    __shared__ int   lds_i[4][64];

    const int lane = threadIdx.x & 63;
    const int wv   = threadIdx.x >> 6;
    const int i    = blockIdx.x * 64 + lane;
    const int ic   = (i < N_PTS) ? i : (N_PTS - 1);
    const float4* tar4 = (const float4*)tar;

    // --- Phase A: per-wave chunk-subset reduce (coalesced) ---
    float bv = INFINITY; int bc = 0;
    #pragma unroll 8
    for (int c = wv; c < NT_CHUNKS; c += 4) {
        float v = pval[c * N_PTS + ic];
        if (v < bv) { bv = v; bc = c; }
    }
    lds_v[wv][lane] = bv;
    lds_i[wv][lane] = bc;
    __syncthreads();

    // --- Phase B: lexicographic (val, chunk) min across waves ---
    float cv = lds_v[0][lane]; int cc = lds_i[0][lane];
    #pragma unroll
    for (int w = 1; w < 4; ++w) {
        float v = lds_v[w][lane]; int c = lds_i[w][lane];
        if (v < cv || (v == cv && c < cc)) { cv = v; cc = c; }
    }
    __syncthreads();

    // --- Phase C: rescan winning chunk, 20 targets per wave ---
    float Tm[4][4];
    #pragma unroll
    for (int a = 0; a < 16; ++a) ((float*)Tm)[a] = T[a];

    const float4 p = ((const float4*)src)[ic];
    const float tx = fmaf(Tm[0][0], p.x, fmaf(Tm[0][1], p.y, fmaf(Tm[0][2], p.z, Tm[0][3] * p.w)));
    const float ty = fmaf(Tm[1][0], p.x, fmaf(Tm[1][1], p.y, fmaf(Tm[1][2], p.z, Tm[1][3] * p.w)));
    const float tz = fmaf(Tm[2][0], p.x, fmaf(Tm[2][1], p.y, fmaf(Tm[2][2], p.z, Tm[2][3] * p.w)));
    const float sx = -2.0f * tx, sy = -2.0f * ty, sz = -2.0f * tz;

    const int jb = cc * CHUNK + wv * RES_PER_WAVE;
    float rv = INFINITY; int rj = 0;
    #pragma unroll 5
    for (int jj = 0; jj < RES_PER_WAVE; ++jj) {
        float4 t = tar4[jb + jj];
        float n3 = fmaf(t.x, t.x, fmaf(t.y, t.y, t.z * t.z));
        float s  = fmaf(sx, t.x, fmaf(sy, t.y, fmaf(sz, t.z, n3)));
        if (s < rv) { rv = s; rj = jb + jj; }
    }
    lds_v[wv][lane] = rv;
    lds_i[wv][lane] = rj;
    __syncthreads();

    // --- Phase D: wave 0 finishes per-source work ---
    if (wv == 0) {
        float fv = lds_v[0][lane]; int bidx = lds_i[0][lane];
        #pragma unroll
        for (int w = 1; w < 4; ++w) {
            float v = lds_v[w][lane]; int j = lds_i[w][lane];
            if (v < fv || (v == fv && j < bidx)) { fv = v; bidx = j; }
        }

        float C[4][4];
        #pragma unroll
        for (int a = 0; a < 16; ++a) ((float*)C)[a] = cs[ic * 16 + a];

        float B[4][3];
        #pragma unroll
        for (int j = 0; j < 4; ++j)
            #pragma unroll
            for (int c = 0; c < 3; ++c)
                B[j][c] = C[j][0]*Tm[c][0] + C[j][1]*Tm[c][1]
                        + C[j][2]*Tm[c][2] + C[j][3]*Tm[c][3];

        const float* ctb = ct + (size_t)bidx * 16;
        float M[3][3];
        #pragma unroll
        for (int r = 0; r < 3; ++r)
            #pragma unroll
            for (int c = 0; c < 3; ++c)
                M[r][c] = Tm[r][0]*B[0][c] + Tm[r][1]*B[1][c]
                        + Tm[r][2]*B[2][c] + Tm[r][3]*B[3][c]
                        + ctb[r * 4 + c];

        const float a_ = M[0][0], b_ = M[0][1], c_ = M[0][2];
        const float d_ = M[1][0], e_ = M[1][1], f_ = M[1][2];
        const float g_ = M[2][0], h_ = M[2][1], i_ = M[2][2];

        const float A0 = e_*i_ - f_*h_;
        const float A1 = f_*g_ - d_*i_;
        const float A2 = d_*h_ - e_*g_;
        const float det = a_*A0 + b_*A1 + c_*A2;
        const float rdet = 1.0f / det;

        float inv[3][3];
        inv[0][0] = A0 * rdet;
        inv[0][1] = (c_*h_ - b_*i_) * rdet;
        inv[0][2] = (b_*f_ - c_*e_) * rdet;
        inv[1][0] = A1 * rdet;
        inv[1][1] = (a_*i_ - c_*g_) * rdet;
        inv[1][2] = (c_*d_ - a_*f_) * rdet;
        inv[2][0] = A2 * rdet;
        inv[2][1] = (b_*g_ - a_*h_) * rdet;
        inv[2][2] = (a_*e_ - b_*d_) * rdet;

        // loss branch: pT = src @ T (columns of T)
        const float p0 = p.x*Tm[0][0] + p.y*Tm[1][0] + p.z*Tm[2][0] + p.w*Tm[3][0];
        const float p1 = p.x*Tm[0][1] + p.y*Tm[1][1] + p.z*Tm[2][1] + p.w*Tm[3][1];
        const float p2 = p.x*Tm[0][2] + p.y*Tm[1][2] + p.z*Tm[2][2] + p.w*Tm[3][2];

        const float4 tp = tar4[bidx];
        const float r0 = tp.x - p0;
        const float r1 = tp.y - p1;
        const float r2 = tp.z - p2;

        float mah = r0*(inv[0][0]*r0 + inv[0][1]*r1 + inv[0][2]*r2)
                  + r1*(inv[1][0]*r0 + inv[1][1]*r1 + inv[1][2]*r2)
                  + r2*(inv[2][0]*r0 + inv[2][1]*r1 + inv[2][2]*r2);
        if (i >= N_PTS) mah = 0.0f;

        // wave reduce (deterministic)
        #pragma unroll
        for (int off = 32; off > 0; off >>= 1)
            mah += __shfl_down(mah, off, 64);

        unsigned int old = 0u;
        if (lane == 0) {
            bsum[blockIdx.x] = mah;
            __threadfence();
            old = atomicAdd(counter, 1u);
        }
        old = __shfl(old, 0, 64);

        // --- Phase E: last block: fixed-order final reduce ---
        if (old == MAH_BLOCKS - 1) {
            __threadfence();   // acquire
            double acc = 0.0;
            for (int s = lane; s < MAH_BLOCKS; s += 64)
                acc += (double)atomicAdd(&bsum[s], 0.0f);   // coherent read
            #pragma unroll
            for (int off = 32; off > 0; off >>= 1)
                acc += __shfl_down(acc, off, 64);
            if (lane == 0)
                out[0] = (float)(acc / (double)N_PTS);
        }
    }
}

extern "C" void kernel_launch(void* const* d_in, const int* in_sizes, int n_in,
                              void* d_out, int out_size, void* d_ws, size_t ws_size,
                              hipStream_t stream) {
    const float* T   = (const float*)d_in[0];
    const float* src = (const float*)d_in[1];
    const float* tar = (const float*)d_in[2];
    const float* cs  = (const float*)d_in[3];
    const float* ct  = (const float*)d_in[4];
    float* out = (float*)d_out;

    char* ws = (char*)d_ws;
    unsigned int* counter = (unsigned int*)ws;             // 4 B
    float* bsum = (float*)(ws + 256);                      // 188 floats
    float* pval = (float*)(ws + 4096);                     // 150*12000*4 = 7.2 MB

    dim3 g1(SRC_BLOCKS, NT_CHUNKS);
    nn_partial_kernel<<<g1, 256, 0, stream>>>(T, src, tar, pval, counter);

    mah_finalize_kernel<<<MAH_BLOCKS, 256, 0, stream>>>(
        T, src, tar, cs, ct, pval, bsum, counter, out);
}